// Round 1
// baseline (521.860 us; speedup 1.0000x reference)
//
#include <hip/hip_runtime.h>
#include <hip/hip_bf16.h>
#include <cstdint>

#define B_SZ 8192
#define NH 16
#define HD 256
#define FH 512

typedef __bf16 bf16x8 __attribute__((ext_vector_type(8)));
typedef float f32x4 __attribute__((ext_vector_type(4)));

// async global->LDS, 16 bytes per lane. lds ptr must be wave-uniform;
// data lands at lds_base + lane*16.
__device__ __forceinline__ void lds_load16(const void* g, void* l) {
  __builtin_amdgcn_global_load_lds(
      (const __attribute__((address_space(1))) unsigned char*)g,
      (__attribute__((address_space(3))) unsigned char*)l, 16, 0, 0);
}

// ---------------- weight convert + transpose: src fp32 [NH][K][N] -> dst bf16 [NH][N][K]
__global__ __launch_bounds__(256) void wcvt_kernel(const float* __restrict__ src,
                                                   __bf16* __restrict__ dst,
                                                   int K, int N) {
  const int tiles_n = N >> 5, tiles_k = K >> 5;
  const int per_head = tiles_n * tiles_k;
  const int bid = blockIdx.x;
  const int head = bid / per_head;
  const int rem = bid - head * per_head;
  const int tk = rem / tiles_n;
  const int tn = rem - tk * tiles_n;
  __shared__ float tile[32][33];
  const float* s = src + ((size_t)head * K + tk * 32) * N + tn * 32;
  const int r = threadIdx.x >> 3;           // 0..31
  const int c4 = (threadIdx.x & 7) * 4;     // 0..28
  float4 v = *(const float4*)(s + (size_t)r * N + c4);
  tile[r][c4 + 0] = v.x; tile[r][c4 + 1] = v.y;
  tile[r][c4 + 2] = v.z; tile[r][c4 + 3] = v.w;
  __syncthreads();
  __bf16 o[4] __attribute__((aligned(8)));
  #pragma unroll
  for (int j = 0; j < 4; ++j) o[j] = (__bf16)tile[c4 + j][r];
  __bf16* d = dst + ((size_t)head * N + tn * 32 + r) * K + tk * 32 + c4;
  *(uint2*)d = *(uint2*)o;
}

// ---------------- prep: rmsnorm1 -> head-mix -> mask -> +x = p ; rmsnorm2 -> h (bf16)
// p_ws: fp32 [NH][B][HD]   h_ws: bf16 [NH][B][HD]
__global__ __launch_bounds__(256) void prep_kernel(const float* __restrict__ x,
                                                   const float* __restrict__ n1w,
                                                   const float* __restrict__ n2w,
                                                   const float* __restrict__ mask,
                                                   float* __restrict__ p_ws,
                                                   __bf16* __restrict__ h_ws) {
  const int b = blockIdx.x;
  const int t = threadIdx.x;
  const int g = t >> 4;     // head this thread produces
  const int li = t & 15;    // sub-block / source head index
  __shared__ float xs[16 * 260];   // padded row stride to cut bank conflicts
  __shared__ float rms1s[16];
  const float* xb = x + (size_t)b * (NH * HD);

  // own 16 elements of head g at columns li*16..li*16+15
  float xv[16];
  float ss = 0.f;
  #pragma unroll
  for (int j = 0; j < 4; ++j) {
    float4 v = *(const float4*)(xb + g * HD + li * 16 + j * 4);
    *(float4*)(xs + g * 260 + li * 16 + j * 4) = v;
    xv[j * 4 + 0] = v.x; xv[j * 4 + 1] = v.y;
    xv[j * 4 + 2] = v.z; xv[j * 4 + 3] = v.w;
    ss += v.x * v.x + v.y * v.y + v.z * v.z + v.w * v.w;
  }
  #pragma unroll
  for (int d = 1; d < 16; d <<= 1) ss += __shfl_xor(ss, d);
  if (li == 0) rms1s[g] = rsqrtf(ss * (1.f / 256.f) + 1e-6f);
  __syncthreads();

  // p[g][c], c = li*16 + k ; source = normed[head li][g*16 + k]
  const float r1 = rms1s[li];
  float pv[16];
  float ss2 = 0.f;
  #pragma unroll
  for (int j = 0; j < 4; ++j) {
    float4 sv = *(const float4*)(xs + li * 260 + g * 16 + j * 4);
    float s4[4] = {sv.x, sv.y, sv.z, sv.w};
    #pragma unroll
    for (int q = 0; q < 4; ++q) {
      const int k = j * 4 + q;
      const int c = li * 16 + k;
      const float mixed = s4[q] * r1 * n1w[g * 16 + k] * mask[g * HD + c];
      const float p = mixed + xv[k];
      pv[k] = p;
      ss2 += p * p;
    }
  }
  #pragma unroll
  for (int d = 1; d < 16; d <<= 1) ss2 += __shfl_xor(ss2, d);
  const float r2 = rsqrtf(ss2 * (1.f / 256.f) + 1e-6f);

  float* pp = p_ws + ((size_t)g * B_SZ + b) * HD + li * 16;
  #pragma unroll
  for (int j = 0; j < 4; ++j) {
    float4 v;
    v.x = pv[j * 4 + 0]; v.y = pv[j * 4 + 1];
    v.z = pv[j * 4 + 2]; v.w = pv[j * 4 + 3];
    *(float4*)(pp + j * 4) = v;
  }
  __bf16 hv[16] __attribute__((aligned(16)));
  #pragma unroll
  for (int k = 0; k < 16; ++k) {
    const int c = li * 16 + k;
    hv[k] = (__bf16)(pv[k] * r2 * n2w[c]);
  }
  __bf16* hp = h_ws + ((size_t)g * B_SZ + b) * HD + li * 16;
  *(uint4*)(hp + 0) = *(uint4*)(hv + 0);
  *(uint4*)(hp + 8) = *(uint4*)(hv + 8);
}

// ---------------- gemm1: per head  S = silu(H W1) * (H W3),  H bf16 [B][256], W*T bf16 [512][256]
// BM=128 BN=64 BK=32, dual-B. grid = 16 * 64 * 8
__global__ __launch_bounds__(256) void gemm1_kernel(const __bf16* __restrict__ h_ws,
                                                    const __bf16* __restrict__ w1t,
                                                    const __bf16* __restrict__ w3t,
                                                    __bf16* __restrict__ s_ws) {
  const int bid = blockIdx.x;
  const int head = bid >> 9;
  const int rem = bid & 511;
  const int mt = rem >> 3, nt = rem & 7;
  const int row0 = mt * 128, col0 = nt * 64;
  const int t = threadIdx.x;
  const int wv = t >> 6, lane = t & 63;
  const int wm = wv >> 1, wn = wv & 1;
  const int mlane = lane & 15, quad = lane >> 4;

  __shared__ __bf16 As[128 * 32];
  __shared__ __bf16 B1s[64 * 32];
  __shared__ __bf16 B3s[64 * 32];

  const __bf16* Ab = h_ws + ((size_t)head * B_SZ + row0) * HD;
  const __bf16* B1b = w1t + ((size_t)head * FH + col0) * HD;
  const __bf16* B3b = w3t + ((size_t)head * FH + col0) * HD;

  f32x4 accg[4][2], accv[4][2];
  #pragma unroll
  for (int i = 0; i < 4; ++i)
    #pragma unroll
    for (int j = 0; j < 2; ++j) {
      accg[i][j] = (f32x4){0.f, 0.f, 0.f, 0.f};
      accv[i][j] = (f32x4){0.f, 0.f, 0.f, 0.f};
    }

  const int arow = t >> 2;          // 0..63
  const int acol = (t & 3) * 8;     // 0,8,16,24

  for (int kk = 0; kk < 8; ++kk) {
    const int k0 = kk * 32;
    lds_load16(Ab + (size_t)arow * HD + k0 + acol, As + wv * 512);
    lds_load16(Ab + (size_t)(arow + 64) * HD + k0 + acol, As + 2048 + wv * 512);
    lds_load16(B1b + (size_t)arow * HD + k0 + acol, B1s + wv * 512);
    lds_load16(B3b + (size_t)arow * HD + k0 + acol, B3s + wv * 512);
    __syncthreads();

    bf16x8 a[4], b1[2], b3[2];
    #pragma unroll
    for (int i = 0; i < 4; ++i)
      a[i] = *(const bf16x8*)(As + (wm * 64 + i * 16 + mlane) * 32 + quad * 8);
    #pragma unroll
    for (int j = 0; j < 2; ++j) {
      b1[j] = *(const bf16x8*)(B1s + (wn * 32 + j * 16 + mlane) * 32 + quad * 8);
      b3[j] = *(const bf16x8*)(B3s + (wn * 32 + j * 16 + mlane) * 32 + quad * 8);
    }
    #pragma unroll
    for (int i = 0; i < 4; ++i)
      #pragma unroll
      for (int j = 0; j < 2; ++j) {
        accg[i][j] = __builtin_amdgcn_mfma_f32_16x16x32_bf16(a[i], b1[j], accg[i][j], 0, 0, 0);
        accv[i][j] = __builtin_amdgcn_mfma_f32_16x16x32_bf16(a[i], b3[j], accv[i][j], 0, 0, 0);
      }
    __syncthreads();
  }

  __bf16* Sb = s_ws + ((size_t)head * B_SZ + row0) * FH + col0;
  #pragma unroll
  for (int i = 0; i < 4; ++i)
    #pragma unroll
    for (int j = 0; j < 2; ++j)
      #pragma unroll
      for (int r = 0; r < 4; ++r) {
        const int rr = wm * 64 + i * 16 + quad * 4 + r;
        const int cc = wn * 32 + j * 16 + mlane;
        const float gg = accg[i][j][r];
        const float vvv = accv[i][j][r];
        const float s = gg / (1.f + __expf(-gg)) * vvv;
        Sb[(size_t)rr * FH + cc] = (__bf16)s;
      }
}

// ---------------- gemm2: per head  out = S W2 + p,  S bf16 [B][512], W2T bf16 [256][512]
// BM=128 BN=128 BK=32. grid = 16 * 64 * 2
__global__ __launch_bounds__(256) void gemm2_kernel(const __bf16* __restrict__ s_ws,
                                                    const __bf16* __restrict__ w2t,
                                                    const float* __restrict__ p_ws,
                                                    float* __restrict__ out) {
  const int bid = blockIdx.x;
  const int head = bid >> 7;
  const int rem = bid & 127;
  const int mt = rem >> 1, nt = rem & 1;
  const int row0 = mt * 128, col0 = nt * 128;
  const int t = threadIdx.x;
  const int wv = t >> 6, lane = t & 63;
  const int wm = wv >> 1, wn = wv & 1;
  const int mlane = lane & 15, quad = lane >> 4;

  __shared__ __bf16 As[128 * 32];
  __shared__ __bf16 Bs[128 * 32];

  const __bf16* Ab = s_ws + ((size_t)head * B_SZ + row0) * FH;
  const __bf16* Bb = w2t + ((size_t)head * HD + col0) * FH;

  f32x4 acc[4][4];
  #pragma unroll
  for (int i = 0; i < 4; ++i)
    #pragma unroll
    for (int j = 0; j < 4; ++j) acc[i][j] = (f32x4){0.f, 0.f, 0.f, 0.f};

  const int arow = t >> 2;
  const int acol = (t & 3) * 8;

  for (int kk = 0; kk < 16; ++kk) {
    const int k0 = kk * 32;
    lds_load16(Ab + (size_t)arow * FH + k0 + acol, As + wv * 512);
    lds_load16(Ab + (size_t)(arow + 64) * FH + k0 + acol, As + 2048 + wv * 512);
    lds_load16(Bb + (size_t)arow * FH + k0 + acol, Bs + wv * 512);
    lds_load16(Bb + (size_t)(arow + 64) * FH + k0 + acol, Bs + 2048 + wv * 512);
    __syncthreads();

    bf16x8 a[4], b[4];
    #pragma unroll
    for (int i = 0; i < 4; ++i)
      a[i] = *(const bf16x8*)(As + (wm * 64 + i * 16 + mlane) * 32 + quad * 8);
    #pragma unroll
    for (int j = 0; j < 4; ++j)
      b[j] = *(const bf16x8*)(Bs + (wn * 64 + j * 16 + mlane) * 32 + quad * 8);
    #pragma unroll
    for (int i = 0; i < 4; ++i)
      #pragma unroll
      for (int j = 0; j < 4; ++j)
        acc[i][j] = __builtin_amdgcn_mfma_f32_16x16x32_bf16(a[i], b[j], acc[i][j], 0, 0, 0);
    __syncthreads();
  }

  const float* Pb = p_ws + ((size_t)head * B_SZ + row0) * HD + col0;
  float* Ob = out + (size_t)row0 * (NH * HD) + head * HD + col0;
  #pragma unroll
  for (int i = 0; i < 4; ++i)
    #pragma unroll
    for (int j = 0; j < 4; ++j)
      #pragma unroll
      for (int r = 0; r < 4; ++r) {
        const int rr = wm * 64 + i * 16 + quad * 4 + r;
        const int cc = wn * 64 + j * 16 + mlane;
        Ob[(size_t)rr * (NH * HD) + cc] = acc[i][j][r] + Pb[(size_t)rr * HD + cc];
      }
}

extern "C" void kernel_launch(void* const* d_in, const int* in_sizes, int n_in,
                              void* d_out, int out_size, void* d_ws, size_t ws_size,
                              hipStream_t stream) {
  const float* x    = (const float*)d_in[0];
  const float* n1w  = (const float*)d_in[1];
  const float* n2w  = (const float*)d_in[2];
  const float* w1   = (const float*)d_in[3];
  const float* w3   = (const float*)d_in[4];
  const float* w2   = (const float*)d_in[5];
  const float* mask = (const float*)d_in[6];
  float* out = (float*)d_out;

  char* ws = (char*)d_ws;
  // ws layout (bytes):
  //   p_ws  fp32 [16][8192][256]  @ 0          (134217728)
  //   h_ws  bf16 [16][8192][256]  @ 134217728  ( 67108864)
  //   s_ws  bf16 [16][8192][512]  @ 201326592  (134217728)
  //   w1t   bf16 [16][512][256]   @ 335544320  (  4194304)
  //   w3t   bf16 [16][512][256]   @ 339738624  (  4194304)
  //   w2t   bf16 [16][256][512]   @ 343932928  (  4194304)
  float*  p_ws = (float*)(ws + 0);
  __bf16* h_ws = (__bf16*)(ws + 134217728);
  __bf16* s_ws = (__bf16*)(ws + 201326592);
  __bf16* w1t  = (__bf16*)(ws + 335544320);
  __bf16* w3t  = (__bf16*)(ws + 339738624);
  __bf16* w2t  = (__bf16*)(ws + 343932928);

  wcvt_kernel<<<2048, 256, 0, stream>>>(w1, w1t, 256, 512);
  wcvt_kernel<<<2048, 256, 0, stream>>>(w3, w3t, 256, 512);
  wcvt_kernel<<<2048, 256, 0, stream>>>(w2, w2t, 512, 256);
  prep_kernel<<<8192, 256, 0, stream>>>(x, n1w, n2w, mask, p_ws, h_ws);
  gemm1_kernel<<<8192, 256, 0, stream>>>(h_ws, w1t, w3t, s_ws);
  gemm2_kernel<<<2048, 256, 0, stream>>>(s_ws, w2t, p_ws, out);
}

// Round 2
// 486.411 us; speedup vs baseline: 1.0729x; 1.0729x over previous
//
#include <hip/hip_runtime.h>
#include <hip/hip_bf16.h>
#include <cstdint>

#define B_SZ 8192
#define NH 16
#define HD 256
#define FH 512

typedef __bf16 bf16x8 __attribute__((ext_vector_type(8)));
typedef float f32x4 __attribute__((ext_vector_type(4)));

// async global->LDS, 16 bytes per lane. lds ptr must be wave-uniform;
// data lands at lds_base + lane*16.
__device__ __forceinline__ void lds_load16(const void* g, void* l) {
  __builtin_amdgcn_global_load_lds(
      (const __attribute__((address_space(1))) unsigned char*)g,
      (__attribute__((address_space(3))) unsigned char*)l, 16, 0, 0);
}

// ---------------- weight convert + transpose (all 3 weights in one launch):
// src fp32 [NH][K][N] -> dst bf16 [NH][N][K]
__global__ __launch_bounds__(256) void wcvt_kernel(const float* __restrict__ w1,
                                                   const float* __restrict__ w3,
                                                   const float* __restrict__ w2,
                                                   __bf16* __restrict__ w1t,
                                                   __bf16* __restrict__ w3t,
                                                   __bf16* __restrict__ w2t) {
  int bid = blockIdx.x;
  const float* src;
  __bf16* dst;
  int K, N;
  if (bid < 2048)      { src = w1; dst = w1t; K = 256; N = 512; }
  else if (bid < 4096) { src = w3; dst = w3t; K = 256; N = 512; bid -= 2048; }
  else                 { src = w2; dst = w2t; K = 512; N = 256; bid -= 4096; }
  const int tiles_n = N >> 5, tiles_k = K >> 5;
  const int per_head = tiles_n * tiles_k;
  const int head = bid / per_head;
  const int rem = bid - head * per_head;
  const int tk = rem / tiles_n;
  const int tn = rem - tk * tiles_n;
  __shared__ float tile[32][33];
  const float* s = src + ((size_t)head * K + tk * 32) * N + tn * 32;
  const int r = threadIdx.x >> 3;           // 0..31
  const int c4 = (threadIdx.x & 7) * 4;     // 0..28
  float4 v = *(const float4*)(s + (size_t)r * N + c4);
  tile[r][c4 + 0] = v.x; tile[r][c4 + 1] = v.y;
  tile[r][c4 + 2] = v.z; tile[r][c4 + 3] = v.w;
  __syncthreads();
  __bf16 o[4] __attribute__((aligned(8)));
  #pragma unroll
  for (int j = 0; j < 4; ++j) o[j] = (__bf16)tile[c4 + j][r];
  __bf16* d = dst + ((size_t)head * N + tn * 32 + r) * K + tk * 32 + c4;
  *(uint2*)d = *(uint2*)o;
}

// ---------------- prep: rmsnorm1 -> head-mix -> mask -> +x = p ; rmsnorm2 -> h
// p_ws: bf16 [NH][B][HD]   h_ws: bf16 [NH][B][HD]
__global__ __launch_bounds__(256) void prep_kernel(const float* __restrict__ x,
                                                   const float* __restrict__ n1w,
                                                   const float* __restrict__ n2w,
                                                   const float* __restrict__ mask,
                                                   __bf16* __restrict__ p_ws,
                                                   __bf16* __restrict__ h_ws) {
  const int b = blockIdx.x;
  const int t = threadIdx.x;
  const int g = t >> 4;     // head this thread produces
  const int li = t & 15;    // sub-block / source head index
  __shared__ float xs[16 * 260];   // padded row stride to cut bank conflicts
  __shared__ float rms1s[16];
  const float* xb = x + (size_t)b * (NH * HD);

  // own 16 elements of head g at columns li*16..li*16+15
  float xv[16];
  float ss = 0.f;
  #pragma unroll
  for (int j = 0; j < 4; ++j) {
    float4 v = *(const float4*)(xb + g * HD + li * 16 + j * 4);
    *(float4*)(xs + g * 260 + li * 16 + j * 4) = v;
    xv[j * 4 + 0] = v.x; xv[j * 4 + 1] = v.y;
    xv[j * 4 + 2] = v.z; xv[j * 4 + 3] = v.w;
    ss += v.x * v.x + v.y * v.y + v.z * v.z + v.w * v.w;
  }
  #pragma unroll
  for (int d = 1; d < 16; d <<= 1) ss += __shfl_xor(ss, d);
  if (li == 0) rms1s[g] = rsqrtf(ss * (1.f / 256.f) + 1e-6f);
  __syncthreads();

  // p[g][c], c = li*16 + k ; source = normed[head li][g*16 + k]
  const float r1 = rms1s[li];
  float pv[16];
  float ss2 = 0.f;
  #pragma unroll
  for (int j = 0; j < 4; ++j) {
    float4 sv = *(const float4*)(xs + li * 260 + g * 16 + j * 4);
    float s4[4] = {sv.x, sv.y, sv.z, sv.w};
    #pragma unroll
    for (int q = 0; q < 4; ++q) {
      const int k = j * 4 + q;
      const int c = li * 16 + k;
      const float mixed = s4[q] * r1 * n1w[g * 16 + k] * mask[g * HD + c];
      const float p = mixed + xv[k];
      pv[k] = p;
      ss2 += p * p;
    }
  }
  #pragma unroll
  for (int d = 1; d < 16; d <<= 1) ss2 += __shfl_xor(ss2, d);
  const float r2 = rsqrtf(ss2 * (1.f / 256.f) + 1e-6f);

  __bf16 pb[16] __attribute__((aligned(16)));
  __bf16 hv[16] __attribute__((aligned(16)));
  #pragma unroll
  for (int k = 0; k < 16; ++k) {
    const int c = li * 16 + k;
    pb[k] = (__bf16)pv[k];
    hv[k] = (__bf16)(pv[k] * r2 * n2w[c]);
  }
  __bf16* pp = p_ws + ((size_t)g * B_SZ + b) * HD + li * 16;
  *(uint4*)(pp + 0) = *(uint4*)(pb + 0);
  *(uint4*)(pp + 8) = *(uint4*)(pb + 8);
  __bf16* hp = h_ws + ((size_t)g * B_SZ + b) * HD + li * 16;
  *(uint4*)(hp + 0) = *(uint4*)(hv + 0);
  *(uint4*)(hp + 8) = *(uint4*)(hv + 8);
}

// ---------------- gemm1: per head  S = silu(H W1) * (H W3)
// H bf16 [B][256], W*T bf16 [512][256]. BM=128 BN=64 BK=64 (two 32-buffers), dual-B.
// XCD swizzle: bid = nt*1024 + head*64 + mt  -> all 8 nt of one A-tile share bid%8.
__global__ __launch_bounds__(256) void gemm1_kernel(const __bf16* __restrict__ h_ws,
                                                    const __bf16* __restrict__ w1t,
                                                    const __bf16* __restrict__ w3t,
                                                    __bf16* __restrict__ s_ws) {
  const int bid = blockIdx.x;
  const int nt = bid >> 10;
  const int q = bid & 1023;
  const int head = q >> 6, mt = q & 63;
  const int row0 = mt * 128, col0 = nt * 64;
  const int t = threadIdx.x;
  const int wv = t >> 6, lane = t & 63;
  const int wm = wv >> 1, wn = wv & 1;
  const int mlane = lane & 15, quad = lane >> 4;

  __shared__ __bf16 As[2 * 128 * 32];   // [ks][row][32]
  __shared__ __bf16 B1s[2 * 64 * 32];
  __shared__ __bf16 B3s[2 * 64 * 32];

  const __bf16* Ab = h_ws + ((size_t)head * B_SZ + row0) * HD;
  const __bf16* B1b = w1t + ((size_t)head * FH + col0) * HD;
  const __bf16* B3b = w3t + ((size_t)head * FH + col0) * HD;

  f32x4 accg[4][2], accv[4][2];
  #pragma unroll
  for (int i = 0; i < 4; ++i)
    #pragma unroll
    for (int j = 0; j < 2; ++j) {
      accg[i][j] = (f32x4){0.f, 0.f, 0.f, 0.f};
      accv[i][j] = (f32x4){0.f, 0.f, 0.f, 0.f};
    }

  const int arow = t >> 2;          // 0..63
  const int acol = (t & 3) * 8;     // 0,8,16,24

  for (int kk = 0; kk < 4; ++kk) {
    const int k0 = kk * 64;
    // k-lo (k0..k0+31) into buffer 0, k-hi into buffer 1
    lds_load16(Ab + (size_t)arow * HD + k0 + acol,             As + wv * 512);
    lds_load16(Ab + (size_t)(arow + 64) * HD + k0 + acol,      As + 2048 + wv * 512);
    lds_load16(Ab + (size_t)arow * HD + k0 + 32 + acol,        As + 4096 + wv * 512);
    lds_load16(Ab + (size_t)(arow + 64) * HD + k0 + 32 + acol, As + 4096 + 2048 + wv * 512);
    lds_load16(B1b + (size_t)arow * HD + k0 + acol,            B1s + wv * 512);
    lds_load16(B1b + (size_t)arow * HD + k0 + 32 + acol,       B1s + 2048 + wv * 512);
    lds_load16(B3b + (size_t)arow * HD + k0 + acol,            B3s + wv * 512);
    lds_load16(B3b + (size_t)arow * HD + k0 + 32 + acol,       B3s + 2048 + wv * 512);
    __syncthreads();

    #pragma unroll
    for (int ks = 0; ks < 2; ++ks) {
      bf16x8 a[4], b1[2], b3[2];
      #pragma unroll
      for (int i = 0; i < 4; ++i)
        a[i] = *(const bf16x8*)(As + ks * 4096 + (wm * 64 + i * 16 + mlane) * 32 + quad * 8);
      #pragma unroll
      for (int j = 0; j < 2; ++j) {
        b1[j] = *(const bf16x8*)(B1s + ks * 2048 + (wn * 32 + j * 16 + mlane) * 32 + quad * 8);
        b3[j] = *(const bf16x8*)(B3s + ks * 2048 + (wn * 32 + j * 16 + mlane) * 32 + quad * 8);
      }
      #pragma unroll
      for (int i = 0; i < 4; ++i)
        #pragma unroll
        for (int j = 0; j < 2; ++j) {
          accg[i][j] = __builtin_amdgcn_mfma_f32_16x16x32_bf16(a[i], b1[j], accg[i][j], 0, 0, 0);
          accv[i][j] = __builtin_amdgcn_mfma_f32_16x16x32_bf16(a[i], b3[j], accv[i][j], 0, 0, 0);
        }
    }
    __syncthreads();
  }

  __bf16* Sb = s_ws + ((size_t)head * B_SZ + row0) * FH + col0;
  #pragma unroll
  for (int i = 0; i < 4; ++i)
    #pragma unroll
    for (int j = 0; j < 2; ++j)
      #pragma unroll
      for (int r = 0; r < 4; ++r) {
        const int rr = wm * 64 + i * 16 + quad * 4 + r;
        const int cc = wn * 32 + j * 16 + mlane;
        const float gg = accg[i][j][r];
        const float vvv = accv[i][j][r];
        const float s = gg / (1.f + __expf(-gg)) * vvv;
        Sb[(size_t)rr * FH + cc] = (__bf16)s;
      }
}

// ---------------- gemm2: per head  out = S W2 + p
// S bf16 [B][512], W2T bf16 [256][512], p bf16. BM=128 BN=128 BK=64 (two 32-buffers).
// XCD swizzle: bid = nt*1024 + head*64 + mt.
__global__ __launch_bounds__(256) void gemm2_kernel(const __bf16* __restrict__ s_ws,
                                                    const __bf16* __restrict__ w2t,
                                                    const __bf16* __restrict__ p_ws,
                                                    float* __restrict__ out) {
  const int bid = blockIdx.x;
  const int nt = bid >> 10;
  const int q = bid & 1023;
  const int head = q >> 6, mt = q & 63;
  const int row0 = mt * 128, col0 = nt * 128;
  const int t = threadIdx.x;
  const int wv = t >> 6, lane = t & 63;
  const int wm = wv >> 1, wn = wv & 1;
  const int mlane = lane & 15, quad = lane >> 4;

  __shared__ __bf16 As[2 * 128 * 32];
  __shared__ __bf16 Bs[2 * 128 * 32];

  const __bf16* Ab = s_ws + ((size_t)head * B_SZ + row0) * FH;
  const __bf16* Bb = w2t + ((size_t)head * HD + col0) * FH;

  f32x4 acc[4][4];
  #pragma unroll
  for (int i = 0; i < 4; ++i)
    #pragma unroll
    for (int j = 0; j < 4; ++j) acc[i][j] = (f32x4){0.f, 0.f, 0.f, 0.f};

  const int arow = t >> 2;
  const int acol = (t & 3) * 8;

  for (int kk = 0; kk < 8; ++kk) {
    const int k0 = kk * 64;
    lds_load16(Ab + (size_t)arow * FH + k0 + acol,             As + wv * 512);
    lds_load16(Ab + (size_t)(arow + 64) * FH + k0 + acol,      As + 2048 + wv * 512);
    lds_load16(Ab + (size_t)arow * FH + k0 + 32 + acol,        As + 4096 + wv * 512);
    lds_load16(Ab + (size_t)(arow + 64) * FH + k0 + 32 + acol, As + 4096 + 2048 + wv * 512);
    lds_load16(Bb + (size_t)arow * FH + k0 + acol,             Bs + wv * 512);
    lds_load16(Bb + (size_t)(arow + 64) * FH + k0 + acol,      Bs + 2048 + wv * 512);
    lds_load16(Bb + (size_t)arow * FH + k0 + 32 + acol,        Bs + 4096 + wv * 512);
    lds_load16(Bb + (size_t)(arow + 64) * FH + k0 + 32 + acol, Bs + 4096 + 2048 + wv * 512);
    __syncthreads();

    #pragma unroll
    for (int ks = 0; ks < 2; ++ks) {
      bf16x8 a[4], b[4];
      #pragma unroll
      for (int i = 0; i < 4; ++i)
        a[i] = *(const bf16x8*)(As + ks * 4096 + (wm * 64 + i * 16 + mlane) * 32 + quad * 8);
      #pragma unroll
      for (int j = 0; j < 4; ++j)
        b[j] = *(const bf16x8*)(Bs + ks * 4096 + (wn * 64 + j * 16 + mlane) * 32 + quad * 8);
      #pragma unroll
      for (int i = 0; i < 4; ++i)
        #pragma unroll
        for (int j = 0; j < 4; ++j)
          acc[i][j] = __builtin_amdgcn_mfma_f32_16x16x32_bf16(a[i], b[j], acc[i][j], 0, 0, 0);
    }
    __syncthreads();
  }

  const __bf16* Pb = p_ws + ((size_t)head * B_SZ + row0) * HD + col0;
  float* Ob = out + (size_t)row0 * (NH * HD) + head * HD + col0;
  #pragma unroll
  for (int i = 0; i < 4; ++i)
    #pragma unroll
    for (int j = 0; j < 4; ++j)
      #pragma unroll
      for (int r = 0; r < 4; ++r) {
        const int rr = wm * 64 + i * 16 + quad * 4 + r;
        const int cc = wn * 64 + j * 16 + mlane;
        Ob[(size_t)rr * (NH * HD) + cc] =
            acc[i][j][r] + (float)Pb[(size_t)rr * HD + cc];
      }
}

extern "C" void kernel_launch(void* const* d_in, const int* in_sizes, int n_in,
                              void* d_out, int out_size, void* d_ws, size_t ws_size,
                              hipStream_t stream) {
  const float* x    = (const float*)d_in[0];
  const float* n1w  = (const float*)d_in[1];
  const float* n2w  = (const float*)d_in[2];
  const float* w1   = (const float*)d_in[3];
  const float* w3   = (const float*)d_in[4];
  const float* w2   = (const float*)d_in[5];
  const float* mask = (const float*)d_in[6];
  float* out = (float*)d_out;

  char* ws = (char*)d_ws;
  // ws layout (bytes):
  //   p_ws  bf16 [16][8192][256]  @ 0          ( 67108864)
  //   h_ws  bf16 [16][8192][256]  @ 67108864   ( 67108864)
  //   s_ws  bf16 [16][8192][512]  @ 134217728  (134217728)
  //   w1t   bf16 [16][512][256]   @ 268435456  (  4194304)
  //   w3t   bf16 [16][512][256]   @ 272629760  (  4194304)
  //   w2t   bf16 [16][256][512]   @ 276824064  (  4194304)
  __bf16* p_ws = (__bf16*)(ws + 0);
  __bf16* h_ws = (__bf16*)(ws + 67108864);
  __bf16* s_ws = (__bf16*)(ws + 134217728);
  __bf16* w1t  = (__bf16*)(ws + 268435456);
  __bf16* w3t  = (__bf16*)(ws + 272629760);
  __bf16* w2t  = (__bf16*)(ws + 276824064);

  wcvt_kernel<<<6144, 256, 0, stream>>>(w1, w3, w2, w1t, w3t, w2t);
  prep_kernel<<<8192, 256, 0, stream>>>(x, n1w, n2w, mask, p_ws, h_ws);
  gemm1_kernel<<<8192, 256, 0, stream>>>(h_ws, w1t, w3t, s_ws);
  gemm2_kernel<<<2048, 256, 0, stream>>>(s_ws, w2t, p_ws, out);
}